// Round 5
// baseline (23925.107 us; speedup 1.0000x reference)
//
#include <hip/hip_runtime.h>
#include <math.h>

#define NN 100000
#define NE 3200000
#define NC 20
#define ND 25
#define NG 1024
#define BN_EPS 1e-5f

__device__ __forceinline__ float sigmoidf_(float x){
    return 1.f/(1.f + __expf(-x));
}
__device__ __forceinline__ float softplusf_(float x){
    return fmaxf(x, 0.f) + log1pf(__expf(-fabsf(x)));
}

// nodeproj row layout per node (stride 80 floats):
//   [fd(20) | sd(20) | fs(20) | ss(20)]
// fd = x @ Wf[0:20] + bf (dst part, bias folded), sd = x @ Ws[0:20] + bs
// fs = x @ Wf[20:40], ss = x @ Ws[20:40]           (src part)
// Split into two passes to keep live regs ~60 (round-3 lesson: spill).
__global__ __launch_bounds__(256) void node_proj_kernel(
    const float* __restrict__ xin,
    const float* __restrict__ Wf, const float* __restrict__ bf,
    const float* __restrict__ Ws, const float* __restrict__ bs,
    float* __restrict__ nodeproj, float* __restrict__ hpre)
{
    __shared__ __align__(16) float sWf[40*NC];
    __shared__ __align__(16) float sWs[40*NC];
    __shared__ float sbf[NC], sbs[NC];
    int tid = threadIdx.x;
    for (int i = tid; i < 40*NC; i += 256){ sWf[i] = Wf[i]; sWs[i] = Ws[i]; }
    if (tid < NC){ sbf[tid] = bf[tid]; sbs[tid] = bs[tid]; }
    __syncthreads();
    int n = blockIdx.x*256 + tid;
    if (n >= NN) return;

    float xv[NC];
    const float4* xr = (const float4*)(xin + (size_t)n*NC);
    #pragma unroll
    for (int q = 0; q < 5; q++){
        float4 t = xr[q];
        xv[4*q+0]=t.x; xv[4*q+1]=t.y; xv[4*q+2]=t.z; xv[4*q+3]=t.w;
    }
    float4* np4 = (float4*)(nodeproj + (size_t)n*80);
    float4* hp4 = (float4*)(hpre + (size_t)n*NC);

    // pass 1: fd, sd (dst parts, bias folded)
    {
        float fd[NC], sd[NC];
        #pragma unroll
        for (int c = 0; c < NC; c++){ fd[c]=sbf[c]; sd[c]=sbs[c]; }
        #pragma unroll
        for (int k = 0; k < NC; k++){
            float xk = xv[k];
            #pragma unroll
            for (int c = 0; c < NC; c++){
                fd[c] += xk * sWf[k*NC + c];
                sd[c] += xk * sWs[k*NC + c];
            }
        }
        #pragma unroll
        for (int q = 0; q < 5; q++){
            np4[q]   = make_float4(fd[4*q],fd[4*q+1],fd[4*q+2],fd[4*q+3]);
            np4[5+q] = make_float4(sd[4*q],sd[4*q+1],sd[4*q+2],sd[4*q+3]);
        }
    }
    // pass 2: fs, ss (src parts)
    {
        float fs[NC], ss[NC];
        #pragma unroll
        for (int c = 0; c < NC; c++){ fs[c]=0.f; ss[c]=0.f; }
        #pragma unroll
        for (int k = 0; k < NC; k++){
            float xk = xv[k];
            #pragma unroll
            for (int c = 0; c < NC; c++){
                fs[c] += xk * sWf[(NC+k)*NC + c];
                ss[c] += xk * sWs[(NC+k)*NC + c];
            }
        }
        #pragma unroll
        for (int q = 0; q < 5; q++){
            np4[10+q] = make_float4(fs[4*q],fs[4*q+1],fs[4*q+2],fs[4*q+3]);
            np4[15+q] = make_float4(ss[4*q],ss[4*q+1],ss[4*q+2],ss[4*q+3]);
            hp4[q]    = make_float4(xv[4*q],xv[4*q+1],xv[4*q+2],xv[4*q+3]);
        }
    }
}

// ---------------- CSR build ----------------
__global__ __launch_bounds__(256) void hist_kernel(
    const int* __restrict__ ei, int* __restrict__ count)
{
    int eid = blockIdx.x*256 + threadIdx.x;
    if (eid < NE) atomicAdd(&count[ei[NE + eid]], 1);
}

__global__ __launch_bounds__(256) void scan1_kernel(
    const int* __restrict__ count, int* __restrict__ rowptr, int* __restrict__ blocksum)
{
    __shared__ int s[256];
    int tid = threadIdx.x;
    int i = blockIdx.x*256 + tid;
    int v = (i < NN) ? count[i] : 0;
    s[tid] = v;
    __syncthreads();
    #pragma unroll
    for (int off = 1; off < 256; off <<= 1){
        int t = (tid >= off) ? s[tid - off] : 0;
        __syncthreads();
        s[tid] += t;
        __syncthreads();
    }
    if (i < NN) rowptr[i] = s[tid] - v;
    if (tid == 255) blocksum[blockIdx.x] = s[255];
}

__global__ __launch_bounds__(512) void scan2_kernel(
    int* __restrict__ blocksum, int nblk)
{
    __shared__ int s[512];
    int tid = threadIdx.x;
    int v = (tid < nblk) ? blocksum[tid] : 0;
    s[tid] = v;
    __syncthreads();
    #pragma unroll
    for (int off = 1; off < 512; off <<= 1){
        int t = (tid >= off) ? s[tid - off] : 0;
        __syncthreads();
        s[tid] += t;
        __syncthreads();
    }
    if (tid < nblk) blocksum[tid] = s[tid] - v;
}

__global__ __launch_bounds__(256) void scan3_kernel(
    int* __restrict__ rowptr, const int* __restrict__ blocksum,
    int* __restrict__ cursor)
{
    int i = blockIdx.x*256 + threadIdx.x;
    if (i < NN){
        int r = rowptr[i] + blocksum[blockIdx.x];
        rowptr[i] = r;
        cursor[i] = r;
        if (i == 0) rowptr[NN] = NE;
    }
}

__global__ __launch_bounds__(256) void scatter_kernel(
    const int* __restrict__ ei, int* __restrict__ cursor,
    int* __restrict__ perm, int* __restrict__ psrc)
{
    int eid = blockIdx.x*256 + threadIdx.x;
    if (eid >= NE) return;
    int d = ei[NE + eid];
    int pos = atomicAdd(&cursor[d], 1);
    perm[pos] = eid;
    psrc[pos] = ei[eid];
}

// ---------------- aggregation: one wave owns one node ----------------
// Channel-chunked inner loop keeps live regs ~70 (no spill).
__global__ __launch_bounds__(256, 4) void agg_kernel(
    const float* __restrict__ eattr,
    const int* __restrict__ rowptr, const int* __restrict__ perm,
    const int* __restrict__ psrc,
    const float* __restrict__ Wf, const float* __restrict__ Ws,
    const float* __restrict__ nodeproj, float* __restrict__ hpre)
{
    __shared__ __align__(16) float sWf[ND*NC];   // Wf rows 40..64
    __shared__ __align__(16) float sWs[ND*NC];
    __shared__ float sdst[4][40];                // fd|sd of 4 owned nodes
    __shared__ float sacc[4][NC];
    int tid = threadIdx.x;
    for (int i = tid; i < ND*NC; i += 256){ sWf[i] = Wf[40*NC + i]; sWs[i] = Ws[40*NC + i]; }
    int sub  = tid >> 6;
    int lane = tid & 63;
    int n = blockIdx.x*4 + sub;      // 25000*4 == NN exactly
    if (lane < 40) sdst[sub][lane] = nodeproj[(size_t)n*80 + lane];
    __syncthreads();

    int start = rowptr[n], end = rowptr[n+1];
    float pmsg[NC];
    #pragma unroll
    for (int c = 0; c < NC; c++) pmsg[c] = 0.f;

    const float4* sWf4 = (const float4*)sWf;
    const float4* sWs4 = (const float4*)sWs;

    for (int i = start + lane; i < end; i += 64){
        int e = perm[i];
        int s = psrc[i];
        const float* er = eattr + (size_t)e*ND;
        float ev[ND];
        #pragma unroll
        for (int j = 0; j < ND; j++) ev[j] = er[j];
        const float4* sp4 = (const float4*)(nodeproj + (size_t)s*80 + 40); // fs|ss
        #pragma unroll
        for (int cq = 0; cq < 5; cq++){
            float4 fsv = sp4[cq];
            float4 ssv = sp4[5+cq];
            float f0 = sdst[sub][4*cq+0]    + fsv.x;
            float f1 = sdst[sub][4*cq+1]    + fsv.y;
            float f2 = sdst[sub][4*cq+2]    + fsv.z;
            float f3 = sdst[sub][4*cq+3]    + fsv.w;
            float s0 = sdst[sub][NC+4*cq+0] + ssv.x;
            float s1 = sdst[sub][NC+4*cq+1] + ssv.y;
            float s2 = sdst[sub][NC+4*cq+2] + ssv.z;
            float s3 = sdst[sub][NC+4*cq+3] + ssv.w;
            #pragma unroll
            for (int j = 0; j < ND; j++){
                float evj = ev[j];
                float4 wf = sWf4[j*5 + cq];
                float4 ws = sWs4[j*5 + cq];
                f0 += evj*wf.x; f1 += evj*wf.y; f2 += evj*wf.z; f3 += evj*wf.w;
                s0 += evj*ws.x; s1 += evj*ws.y; s2 += evj*ws.z; s3 += evj*ws.w;
            }
            pmsg[4*cq+0] += sigmoidf_(f0) * softplusf_(s0);
            pmsg[4*cq+1] += sigmoidf_(f1) * softplusf_(s1);
            pmsg[4*cq+2] += sigmoidf_(f2) * softplusf_(s2);
            pmsg[4*cq+3] += sigmoidf_(f3) * softplusf_(s3);
        }
    }
    // 64-lane butterfly reduction per channel
    #pragma unroll
    for (int c = 0; c < NC; c++){
        float v = pmsg[c];
        v += __shfl_xor(v, 1);
        v += __shfl_xor(v, 2);
        v += __shfl_xor(v, 4);
        v += __shfl_xor(v, 8);
        v += __shfl_xor(v, 16);
        v += __shfl_xor(v, 32);
        pmsg[c] = v;
    }
    if (lane == 0){
        #pragma unroll
        for (int c = 0; c < NC; c++) sacc[sub][c] = pmsg[c];
    }
    __syncthreads();
    if (lane < NC){
        size_t o = (size_t)n*NC + lane;
        hpre[o] = hpre[o] + sacc[sub][lane];   // hpre pre-initialized to x
    }
}

// ---------------- BN / pool / head ----------------
__global__ __launch_bounds__(256) void bn_stats_kernel(
    const float* __restrict__ hpre, float* __restrict__ stats)
{
    __shared__ float ssum[NC], ssq[NC];
    int tid = threadIdx.x;
    if (tid < NC){ ssum[tid] = 0.f; ssq[tid] = 0.f; }
    __syncthreads();
    const int total = NN*NC;
    for (int i = blockIdx.x*256 + tid; i < total; i += gridDim.x*256){
        float v = hpre[i];
        int c = i % NC;
        atomicAdd(&ssum[c], v);
        atomicAdd(&ssq[c], v*v);
    }
    __syncthreads();
    if (tid < NC){
        atomicAdd(&stats[tid], ssum[tid]);
        atomicAdd(&stats[NC + tid], ssq[tid]);
    }
}

__global__ void bn_finalize_kernel(float* __restrict__ stats,
    const float* __restrict__ gamma, const float* __restrict__ beta)
{
    int c = threadIdx.x;
    if (c < NC){
        float mu  = stats[c] / (float)NN;
        float var = stats[NC + c] / (float)NN - mu*mu;
        float scale = gamma[c] * rsqrtf(var + BN_EPS);
        stats[2*NC + c] = scale;
        stats[3*NC + c] = beta[c] - mu*scale;
    }
}

__global__ __launch_bounds__(256) void bn_apply_kernel(
    const float* __restrict__ hpre, const float* __restrict__ stats,
    float* __restrict__ h)
{
    int i = blockIdx.x*256 + threadIdx.x;
    if (i >= NN*NC) return;
    int c = i % NC;
    h[i] = hpre[i] * stats[2*NC + c] + stats[3*NC + c];
}

__device__ __forceinline__ int lower_bound_i(const int* __restrict__ a, int n, int v){
    int lo = 0, hi = n;
    while (lo < hi){ int mid = (lo + hi) >> 1; if (a[mid] < v) lo = mid + 1; else hi = mid; }
    return lo;
}

__global__ __launch_bounds__(256) void pool_kernel(
    const float* __restrict__ h, const int* __restrict__ batch,
    float* __restrict__ pooled)
{
    __shared__ float acc[NC];
    __shared__ int sbound[2];
    int g = blockIdx.x;
    int tid = threadIdx.x;
    if (tid < NC) acc[tid] = 0.f;
    if (tid == 0){
        sbound[0] = lower_bound_i(batch, NN, g);
        sbound[1] = lower_bound_i(batch, NN, g + 1);
    }
    __syncthreads();
    int start = sbound[0], end = sbound[1];
    for (int i = start*NC + tid; i < end*NC; i += 256)
        atomicAdd(&acc[i % NC], h[i]);
    __syncthreads();
    if (tid < NC){
        float cnt = (float)(end - start);
        pooled[g*NC + tid] = acc[tid] / fmaxf(cnt, 1.f);
    }
}

__global__ __launch_bounds__(256) void head_kernel(
    const float* __restrict__ pooled,
    const float* __restrict__ W1, const float* __restrict__ c1,
    const float* __restrict__ W2, const float* __restrict__ c2,
    float* __restrict__ y)
{
    int g = blockIdx.x*256 + threadIdx.x;
    if (g >= NG) return;
    float p[NC], t[NC];
    #pragma unroll
    for (int c = 0; c < NC; c++) p[c] = pooled[g*NC + c];
    #pragma unroll
    for (int j = 0; j < NC; j++){
        float a = c1[j];
        #pragma unroll
        for (int k = 0; k < NC; k++) a += p[k] * W1[k*NC + j];
        t[j] = (a > 0.f) ? a : 0.01f * a;
    }
    #pragma unroll
    for (int j = 0; j < NC; j++){
        float a = c2[j];
        #pragma unroll
        for (int k = 0; k < NC; k++) a += t[k] * W2[k*NC + j];
        y[g*NC + j] = a;
    }
}

extern "C" void kernel_launch(void* const* d_in, const int* in_sizes, int n_in,
                              void* d_out, int out_size, void* d_ws, size_t ws_size,
                              hipStream_t stream)
{
    (void)in_sizes; (void)n_in; (void)out_size; (void)ws_size;
    const float* x    = (const float*)d_in[0];
    const int*   ei   = (const int*)d_in[1];
    const float* ea   = (const float*)d_in[2];
    const int*   batch= (const int*)d_in[3];
    const float* Wf0 = (const float*)d_in[4];
    const float* bf0 = (const float*)d_in[5];
    const float* Ws0 = (const float*)d_in[6];
    const float* bs0 = (const float*)d_in[7];
    const float* g0  = (const float*)d_in[8];
    const float* be0 = (const float*)d_in[9];
    const float* Wf1 = (const float*)d_in[10];
    const float* bf1 = (const float*)d_in[11];
    const float* Ws1 = (const float*)d_in[12];
    const float* bs1 = (const float*)d_in[13];
    const float* g1  = (const float*)d_in[14];
    const float* be1 = (const float*)d_in[15];
    const float* W1  = (const float*)d_in[16];
    const float* c1  = (const float*)d_in[17];
    const float* W2  = (const float*)d_in[18];
    const float* c2  = (const float*)d_in[19];
    float* out = (float*)d_out;

    char* ws = (char*)d_ws;
    float* nodeproj = (float*)(ws);                    // 32,000,000 B
    float* hpre     = (float*)(ws + 32000000);         //  8,000,000 B
    float* h        = (float*)(ws + 40000000);         //  8,000,000 B
    float* stats    = (float*)(ws + 48000000);         //        512 B
    float* pooled   = (float*)(ws + 48000512);         //     81,920 B (+pad->48083456)
    int*   rowptr   = (int*)  (ws + 48083456);         //    400,384 B
    int*   cursor   = (int*)  (ws + 48483840);         //    400,384 B
    int*   count    = (int*)  (ws + 48884224);         //    400,384 B
    int*   blocksum = (int*)  (ws + 49284608);         //      4,096 B
    int*   perm     = (int*)  (ws + 49288704);         // 12,800,000 B
    int*   psrc     = (int*)  (ws + 62088704);         // 12,800,000 B

    const int nblk_node = (NN + 255)/256;    // 391
    const int nblk_edge = NE/256;            // 12500
    const int nblk_app  = (NN*NC + 255)/256; // 7813

    // ---- CSR build (shared by both layers) ----
    hipMemsetAsync(count, 0, NN*sizeof(int), stream);
    hist_kernel<<<nblk_edge,256,0,stream>>>(ei, count);
    scan1_kernel<<<nblk_node,256,0,stream>>>(count, rowptr, blocksum);
    scan2_kernel<<<1,512,0,stream>>>(blocksum, nblk_node);
    scan3_kernel<<<nblk_node,256,0,stream>>>(rowptr, blocksum, cursor);
    scatter_kernel<<<nblk_edge,256,0,stream>>>(ei, cursor, perm, psrc);

    // ---- layer 0 ----
    node_proj_kernel<<<nblk_node,256,0,stream>>>(x, Wf0, bf0, Ws0, bs0, nodeproj, hpre);
    agg_kernel<<<NN/4,256,0,stream>>>(ea, rowptr, perm, psrc, Wf0, Ws0, nodeproj, hpre);
    hipMemsetAsync(stats, 0, 2*NC*sizeof(float), stream);
    bn_stats_kernel<<<1024,256,0,stream>>>(hpre, stats);
    bn_finalize_kernel<<<1,64,0,stream>>>(stats, g0, be0);
    bn_apply_kernel<<<nblk_app,256,0,stream>>>(hpre, stats, h);

    // ---- layer 1 ----
    node_proj_kernel<<<nblk_node,256,0,stream>>>(h, Wf1, bf1, Ws1, bs1, nodeproj, hpre);
    agg_kernel<<<NN/4,256,0,stream>>>(ea, rowptr, perm, psrc, Wf1, Ws1, nodeproj, hpre);
    hipMemsetAsync(stats, 0, 2*NC*sizeof(float), stream);
    bn_stats_kernel<<<1024,256,0,stream>>>(hpre, stats);
    bn_finalize_kernel<<<1,64,0,stream>>>(stats, g1, be1);
    bn_apply_kernel<<<nblk_app,256,0,stream>>>(hpre, stats, h);

    // ---- pool + head ----
    pool_kernel<<<NG,256,0,stream>>>(h, batch, pooled);
    head_kernel<<<(NG+255)/256,256,0,stream>>>(pooled, W1, c1, W2, c2, out);
}

// Round 7
// 2501.690 us; speedup vs baseline: 9.5636x; 9.5636x over previous
//
#include <hip/hip_runtime.h>
#include <math.h>

#define NN 100000
#define NE 3200000
#define NC 20
#define ND 25
#define NG 1024
#define BN_EPS 1e-5f

__device__ __forceinline__ float sigmoidf_(float x){
    return 1.f/(1.f + __expf(-x));
}
__device__ __forceinline__ float softplusf_(float x){
    return fmaxf(x, 0.f) + log1pf(__expf(-fabsf(x)));
}

// nodeproj row layout per node (stride 80 floats):
//   [fd(20) | sd(20) | fs(20) | ss(20)]
__global__ __launch_bounds__(256) void node_proj_kernel(
    const float* __restrict__ xin,
    const float* __restrict__ Wf, const float* __restrict__ bf,
    const float* __restrict__ Ws, const float* __restrict__ bs,
    float* __restrict__ nodeproj, float* __restrict__ hpre)
{
    __shared__ __align__(16) float sWf[40*NC];
    __shared__ __align__(16) float sWs[40*NC];
    __shared__ float sbf[NC], sbs[NC];
    int tid = threadIdx.x;
    for (int i = tid; i < 40*NC; i += 256){ sWf[i] = Wf[i]; sWs[i] = Ws[i]; }
    if (tid < NC){ sbf[tid] = bf[tid]; sbs[tid] = bs[tid]; }
    __syncthreads();
    int n = blockIdx.x*256 + tid;
    if (n >= NN) return;

    float xv[NC];
    const float4* xr = (const float4*)(xin + (size_t)n*NC);
    #pragma unroll
    for (int q = 0; q < 5; q++){
        float4 t = xr[q];
        xv[4*q+0]=t.x; xv[4*q+1]=t.y; xv[4*q+2]=t.z; xv[4*q+3]=t.w;
    }
    float4* np4 = (float4*)(nodeproj + (size_t)n*80);
    float4* hp4 = (float4*)(hpre + (size_t)n*NC);

    // pass 1: fd, sd (dst parts, bias folded)
    {
        float fd[NC], sd[NC];
        #pragma unroll
        for (int c = 0; c < NC; c++){ fd[c]=sbf[c]; sd[c]=sbs[c]; }
        #pragma unroll
        for (int k = 0; k < NC; k++){
            float xk = xv[k];
            #pragma unroll
            for (int c = 0; c < NC; c++){
                fd[c] += xk * sWf[k*NC + c];
                sd[c] += xk * sWs[k*NC + c];
            }
        }
        #pragma unroll
        for (int q = 0; q < 5; q++){
            np4[q]   = make_float4(fd[4*q],fd[4*q+1],fd[4*q+2],fd[4*q+3]);
            np4[5+q] = make_float4(sd[4*q],sd[4*q+1],sd[4*q+2],sd[4*q+3]);
        }
    }
    // pass 2: fs, ss (src parts)
    {
        float fs[NC], ss[NC];
        #pragma unroll
        for (int c = 0; c < NC; c++){ fs[c]=0.f; ss[c]=0.f; }
        #pragma unroll
        for (int k = 0; k < NC; k++){
            float xk = xv[k];
            #pragma unroll
            for (int c = 0; c < NC; c++){
                fs[c] += xk * sWf[(NC+k)*NC + c];
                ss[c] += xk * sWs[(NC+k)*NC + c];
            }
        }
        #pragma unroll
        for (int q = 0; q < 5; q++){
            np4[10+q] = make_float4(fs[4*q],fs[4*q+1],fs[4*q+2],fs[4*q+3]);
            np4[15+q] = make_float4(ss[4*q],ss[4*q+1],ss[4*q+2],ss[4*q+3]);
            hp4[q]    = make_float4(xv[4*q],xv[4*q+1],xv[4*q+2],xv[4*q+3]);
        }
    }
}

// ---------------- CSR build ----------------
__global__ __launch_bounds__(256) void hist_kernel(
    const int* __restrict__ ei, int* __restrict__ count)
{
    int eid = blockIdx.x*256 + threadIdx.x;
    if (eid < NE) atomicAdd(&count[ei[NE + eid]], 1);
}

__global__ __launch_bounds__(256) void scan1_kernel(
    const int* __restrict__ count, int* __restrict__ rowptr, int* __restrict__ blocksum)
{
    __shared__ int s[256];
    int tid = threadIdx.x;
    int i = blockIdx.x*256 + tid;
    int v = (i < NN) ? count[i] : 0;
    s[tid] = v;
    __syncthreads();
    #pragma unroll
    for (int off = 1; off < 256; off <<= 1){
        int t = (tid >= off) ? s[tid - off] : 0;
        __syncthreads();
        s[tid] += t;
        __syncthreads();
    }
    if (i < NN) rowptr[i] = s[tid] - v;
    if (tid == 255) blocksum[blockIdx.x] = s[255];
}

__global__ __launch_bounds__(512) void scan2_kernel(
    int* __restrict__ blocksum, int nblk)
{
    __shared__ int s[512];
    int tid = threadIdx.x;
    int v = (tid < nblk) ? blocksum[tid] : 0;
    s[tid] = v;
    __syncthreads();
    #pragma unroll
    for (int off = 1; off < 512; off <<= 1){
        int t = (tid >= off) ? s[tid - off] : 0;
        __syncthreads();
        s[tid] += t;
        __syncthreads();
    }
    if (tid < nblk) blocksum[tid] = s[tid] - v;
}

__global__ __launch_bounds__(256) void scan3_kernel(
    int* __restrict__ rowptr, const int* __restrict__ blocksum,
    int* __restrict__ cursor)
{
    int i = blockIdx.x*256 + threadIdx.x;
    if (i < NN){
        int r = rowptr[i] + blocksum[blockIdx.x];
        rowptr[i] = r;
        cursor[i] = r;
        if (i == 0) rowptr[NN] = NE;
    }
}

// ipos[eid] = CSR slot of edge eid (edges grouped by dst)
__global__ __launch_bounds__(256) void scatter_kernel(
    const int* __restrict__ ei, int* __restrict__ cursor,
    int* __restrict__ ipos)
{
    int eid = blockIdx.x*256 + threadIdx.x;
    if (eid >= NE) return;
    int d = ei[NE + eid];
    ipos[eid] = atomicAdd(&cursor[d], 1);
}

// ---------------- per-edge message (edge-order, round-2-proven codegen) ----
// Writes msg to CSR slot instead of atomicAdd. No persistent accumulators.
__global__ __launch_bounds__(256) void msg_kernel(
    const float* __restrict__ eattr, const int* __restrict__ ei,
    const int* __restrict__ ipos,
    const float* __restrict__ Wf, const float* __restrict__ Ws,
    const float* __restrict__ nodeproj, float* __restrict__ msgbuf)
{
    __shared__ __align__(16) float sWf[ND*NC];   // Wf rows 40..64 (edge part)
    __shared__ __align__(16) float sWs[ND*NC];
    __shared__ float se[256*ND];                 // staged edge_attr tile
    int tid = threadIdx.x;
    for (int i = tid; i < ND*NC; i += 256){ sWf[i] = Wf[40*NC + i]; sWs[i] = Ws[40*NC + i]; }
    size_t base = (size_t)blockIdx.x * 256;
    for (int i = tid; i < 256*ND; i += 256) se[i] = eattr[base*ND + i];
    __syncthreads();

    int eid = (int)base + tid;
    int srcn = ei[eid];
    int dstn = ei[NE + eid];
    int pos  = ipos[eid];

    float ev[ND];
    #pragma unroll
    for (int j = 0; j < ND; j++) ev[j] = se[tid*ND + j];

    const float4* npd4 = (const float4*)(nodeproj + (size_t)dstn*80);      // fd|sd
    const float4* nps4 = (const float4*)(nodeproj + (size_t)srcn*80 + 40); // fs|ss
    const float4* sWf4 = (const float4*)sWf;
    const float4* sWs4 = (const float4*)sWs;
    float4* mrow = (float4*)(msgbuf + (size_t)pos*NC);   // 80B-aligned

    #pragma unroll
    for (int cq = 0; cq < 5; cq++){
        float4 fd4 = npd4[cq];
        float4 sd4 = npd4[5+cq];
        float4 fs4 = nps4[cq];
        float4 ss4 = nps4[5+cq];
        float f0 = fd4.x + fs4.x, f1 = fd4.y + fs4.y, f2 = fd4.z + fs4.z, f3 = fd4.w + fs4.w;
        float s0 = sd4.x + ss4.x, s1 = sd4.y + ss4.y, s2 = sd4.z + ss4.z, s3 = sd4.w + ss4.w;
        #pragma unroll
        for (int j = 0; j < ND; j++){
            float evj = ev[j];
            float4 wf = sWf4[j*5 + cq];
            float4 ws = sWs4[j*5 + cq];
            f0 += evj*wf.x; f1 += evj*wf.y; f2 += evj*wf.z; f3 += evj*wf.w;
            s0 += evj*ws.x; s1 += evj*ws.y; s2 += evj*ws.z; s3 += evj*ws.w;
        }
        float4 m;
        m.x = sigmoidf_(f0) * softplusf_(s0);
        m.y = sigmoidf_(f1) * softplusf_(s1);
        m.z = sigmoidf_(f2) * softplusf_(s2);
        m.w = sigmoidf_(f3) * softplusf_(s3);
        mrow[cq] = m;
    }
}

// ---------------- segment reduce: thread per (node, channel) ----------------
__global__ __launch_bounds__(256) void reduce_kernel(
    const float* __restrict__ msgbuf, const int* __restrict__ rowptr,
    float* __restrict__ hpre)
{
    int idx = blockIdx.x*256 + threadIdx.x;
    if (idx >= NN*NC) return;
    int n = idx / NC;
    int c = idx - n*NC;
    int start = rowptr[n], end = rowptr[n+1];
    float acc = hpre[idx];                 // x residual pre-seeded
    for (int k = start; k < end; k++)
        acc += msgbuf[(size_t)k*NC + c];   // coalesced within node segment
    hpre[idx] = acc;
}

// ---------------- fallback (ws too small): round-2 atomic edge kernel ------
__global__ __launch_bounds__(256) void edge_atomic_kernel(
    const float* __restrict__ eattr, const int* __restrict__ ei,
    const float* __restrict__ Wf, const float* __restrict__ Ws,
    const float* __restrict__ nodeproj, float* __restrict__ hpre)
{
    __shared__ __align__(16) float sWf[ND*NC];
    __shared__ __align__(16) float sWs[ND*NC];
    __shared__ float se[256*ND];
    int tid = threadIdx.x;
    for (int i = tid; i < ND*NC; i += 256){ sWf[i] = Wf[40*NC + i]; sWs[i] = Ws[40*NC + i]; }
    size_t base = (size_t)blockIdx.x * 256;
    for (int i = tid; i < 256*ND; i += 256) se[i] = eattr[base*ND + i];
    __syncthreads();

    int eid = (int)base + tid;
    int srcn = ei[eid];
    int dstn = ei[NE + eid];
    const float* npd = nodeproj + (size_t)dstn*80;
    const float* nps = nodeproj + (size_t)srcn*80 + 40;
    float* dsto = hpre + (size_t)dstn*NC;
    #pragma unroll
    for (int c = 0; c < NC; c++){
        float f = npd[c]      + nps[c];
        float s = npd[NC + c] + nps[NC + c];
        #pragma unroll
        for (int j = 0; j < ND; j++){
            float evj = se[tid*ND + j];
            f += evj * sWf[j*NC + c];
            s += evj * sWs[j*NC + c];
        }
        atomicAdd(dsto + c, sigmoidf_(f) * softplusf_(s));
    }
}

// ---------------- BN / pool / head ----------------
__global__ __launch_bounds__(256) void bn_stats_kernel(
    const float* __restrict__ hpre, float* __restrict__ stats)
{
    __shared__ float ssum[NC], ssq[NC];
    int tid = threadIdx.x;
    if (tid < NC){ ssum[tid] = 0.f; ssq[tid] = 0.f; }
    __syncthreads();
    const int total = NN*NC;
    for (int i = blockIdx.x*256 + tid; i < total; i += gridDim.x*256){
        float v = hpre[i];
        int c = i % NC;
        atomicAdd(&ssum[c], v);
        atomicAdd(&ssq[c], v*v);
    }
    __syncthreads();
    if (tid < NC){
        atomicAdd(&stats[tid], ssum[tid]);
        atomicAdd(&stats[NC + tid], ssq[tid]);
    }
}

__global__ void bn_finalize_kernel(float* __restrict__ stats,
    const float* __restrict__ gamma, const float* __restrict__ beta)
{
    int c = threadIdx.x;
    if (c < NC){
        float mu  = stats[c] / (float)NN;
        float var = stats[NC + c] / (float)NN - mu*mu;
        float scale = gamma[c] * rsqrtf(var + BN_EPS);
        stats[2*NC + c] = scale;
        stats[3*NC + c] = beta[c] - mu*scale;
    }
}

__global__ __launch_bounds__(256) void bn_apply_kernel(
    const float* __restrict__ hpre, const float* __restrict__ stats,
    float* __restrict__ h)
{
    int i = blockIdx.x*256 + threadIdx.x;
    if (i >= NN*NC) return;
    int c = i % NC;
    h[i] = hpre[i] * stats[2*NC + c] + stats[3*NC + c];
}

__device__ __forceinline__ int lower_bound_i(const int* __restrict__ a, int n, int v){
    int lo = 0, hi = n;
    while (lo < hi){ int mid = (lo + hi) >> 1; if (a[mid] < v) lo = mid + 1; else hi = mid; }
    return lo;
}

__global__ __launch_bounds__(256) void pool_kernel(
    const float* __restrict__ h, const int* __restrict__ batch,
    float* __restrict__ pooled)
{
    __shared__ float acc[NC];
    __shared__ int sbound[2];
    int g = blockIdx.x;
    int tid = threadIdx.x;
    if (tid < NC) acc[tid] = 0.f;
    if (tid == 0){
        sbound[0] = lower_bound_i(batch, NN, g);
        sbound[1] = lower_bound_i(batch, NN, g + 1);
    }
    __syncthreads();
    int start = sbound[0], end = sbound[1];
    for (int i = start*NC + tid; i < end*NC; i += 256)
        atomicAdd(&acc[i % NC], h[i]);
    __syncthreads();
    if (tid < NC){
        float cnt = (float)(end - start);
        pooled[g*NC + tid] = acc[tid] / fmaxf(cnt, 1.f);
    }
}

__global__ __launch_bounds__(256) void head_kernel(
    const float* __restrict__ pooled,
    const float* __restrict__ W1, const float* __restrict__ c1,
    const float* __restrict__ W2, const float* __restrict__ c2,
    float* __restrict__ y)
{
    int g = blockIdx.x*256 + threadIdx.x;
    if (g >= NG) return;
    float p[NC], t[NC];
    #pragma unroll
    for (int c = 0; c < NC; c++) p[c] = pooled[g*NC + c];
    #pragma unroll
    for (int j = 0; j < NC; j++){
        float a = c1[j];
        #pragma unroll
        for (int k = 0; k < NC; k++) a += p[k] * W1[k*NC + j];
        t[j] = (a > 0.f) ? a : 0.01f * a;
    }
    #pragma unroll
    for (int j = 0; j < NC; j++){
        float a = c2[j];
        #pragma unroll
        for (int k = 0; k < NC; k++) a += t[k] * W2[k*NC + j];
        y[g*NC + j] = a;
    }
}

extern "C" void kernel_launch(void* const* d_in, const int* in_sizes, int n_in,
                              void* d_out, int out_size, void* d_ws, size_t ws_size,
                              hipStream_t stream)
{
    (void)in_sizes; (void)n_in; (void)out_size;
    const float* x    = (const float*)d_in[0];
    const int*   ei   = (const int*)d_in[1];
    const float* ea   = (const float*)d_in[2];
    const int*   batch= (const int*)d_in[3];
    const float* Wf0 = (const float*)d_in[4];
    const float* bf0 = (const float*)d_in[5];
    const float* Ws0 = (const float*)d_in[6];
    const float* bs0 = (const float*)d_in[7];
    const float* g0  = (const float*)d_in[8];
    const float* be0 = (const float*)d_in[9];
    const float* Wf1 = (const float*)d_in[10];
    const float* bf1 = (const float*)d_in[11];
    const float* Ws1 = (const float*)d_in[12];
    const float* bs1 = (const float*)d_in[13];
    const float* g1  = (const float*)d_in[14];
    const float* be1 = (const float*)d_in[15];
    const float* W1  = (const float*)d_in[16];
    const float* c1  = (const float*)d_in[17];
    const float* W2  = (const float*)d_in[18];
    const float* c2  = (const float*)d_in[19];
    float* out = (float*)d_out;

    char* ws = (char*)d_ws;
    float* nodeproj = (float*)(ws);                    // 32,000,000 B
    float* hpre     = (float*)(ws + 32000000);         //  8,000,000 B
    float* h        = (float*)(ws + 40000000);         //  8,000,000 B
    float* stats    = (float*)(ws + 48000000);         //        512 B
    float* pooled   = (float*)(ws + 48000512);         //     81,920 B
    int*   rowptr   = (int*)  (ws + 48083456);         //    400,384 B
    int*   cursor   = (int*)  (ws + 48483840);         //    400,384 B
    int*   count    = (int*)  (ws + 48884224);         //    400,384 B
    int*   blocksum = (int*)  (ws + 49284608);         //      4,096 B
    int*   ipos     = (int*)  (ws + 49288704);         // 12,800,000 B
    float* msgbuf   = (float*)(ws + 62093824);         // 256,000,000 B
    const size_t WS_NEEDED = 62093824ULL + 256000000ULL;   // ~318 MB
    const bool use_msgbuf = (ws_size >= WS_NEEDED);

    const int nblk_node = (NN + 255)/256;    // 391
    const int nblk_edge = NE/256;            // 12500
    const int nblk_app  = (NN*NC + 255)/256; // 7813

    // ---- CSR build (shared by both layers) ----
    hipMemsetAsync(count, 0, NN*sizeof(int), stream);
    hist_kernel<<<nblk_edge,256,0,stream>>>(ei, count);
    scan1_kernel<<<nblk_node,256,0,stream>>>(count, rowptr, blocksum);
    scan2_kernel<<<1,512,0,stream>>>(blocksum, nblk_node);
    scan3_kernel<<<nblk_node,256,0,stream>>>(rowptr, blocksum, cursor);
    if (use_msgbuf)
        scatter_kernel<<<nblk_edge,256,0,stream>>>(ei, cursor, ipos);

    for (int L = 0; L < 2; L++){
        const float* xin = (L == 0) ? x : h;
        const float* Wf  = (L == 0) ? Wf0 : Wf1;
        const float* bfv = (L == 0) ? bf0 : bf1;
        const float* Wsm = (L == 0) ? Ws0 : Ws1;
        const float* bsv = (L == 0) ? bs0 : bs1;
        const float* gam = (L == 0) ? g0  : g1;
        const float* bet = (L == 0) ? be0 : be1;

        node_proj_kernel<<<nblk_node,256,0,stream>>>(xin, Wf, bfv, Wsm, bsv, nodeproj, hpre);
        if (use_msgbuf){
            msg_kernel<<<nblk_edge,256,0,stream>>>(ea, ei, ipos, Wf, Wsm, nodeproj, msgbuf);
            reduce_kernel<<<nblk_app,256,0,stream>>>(msgbuf, rowptr, hpre);
        } else {
            edge_atomic_kernel<<<nblk_edge,256,0,stream>>>(ea, ei, Wf, Wsm, nodeproj, hpre);
        }
        hipMemsetAsync(stats, 0, 2*NC*sizeof(float), stream);
        bn_stats_kernel<<<1024,256,0,stream>>>(hpre, stats);
        bn_finalize_kernel<<<1,64,0,stream>>>(stats, gam, bet);
        bn_apply_kernel<<<nblk_app,256,0,stream>>>(hpre, stats, h);
    }

    // ---- pool + head ----
    pool_kernel<<<NG,256,0,stream>>>(h, batch, pooled);
    head_kernel<<<(NG+255)/256,256,0,stream>>>(pooled, W1, c1, W2, c2, out);
}